// Round 8
// baseline (306.579 us; speedup 1.0000x reference)
//
#include <hip/hip_runtime.h>

// GCN on MI355X — round 8: parallelize k_fine; fuse agg+MLP (z never hits HBM).
//  - Round-7 profile: k_fine 51 us at 3.5% occupancy — only 98 blocks on
//    256 CUs. Fix: 391 buckets of 256 nodes (32KB window, still single-owner
//    L2-contained) x 512 threads.
//  - k_zmlp: cv is dst-sorted so a block's 128 rows = contiguous cv range.
//    Each wave aggregates its 32 rows into a wave-private LDS tile (bf16,
//    stride-68 padding: balanced banks + 16B-aligned b128), then runs the
//    MFMA MLP reading A-frags from LDS. No barriers, no z traffic (51 MB).
//  - k_part/k_bscan/k_q/prepB unchanged in structure.

#define HD 128
#define HD2 256
#define BSHIFT 8             // 256 nodes per bucket -> 391 buckets
#define BNODES 256
#define SRCBITS 17           // N=100000 < 2^17

typedef __attribute__((ext_vector_type(8))) short bf8_t;   // 8 x bf16 (4 VGPR)
typedef __attribute__((ext_vector_type(4))) float f32x4;

static inline size_t align256(size_t x) { return (x + 255) & ~(size_t)255; }

__device__ inline ushort f2bf(float f) {            // RNE f32 -> bf16
    uint u = __float_as_uint(f);
    uint r = u + 0x7fffu + ((u >> 16) & 1u);
    return (ushort)(r >> 16);
}
__device__ inline uint packbf(float a, float b) {
    return (uint)f2bf(a) | ((uint)f2bf(b) << 16);
}

// Phase 1: stream edges once, partition into 391 dst-buckets via LDS ranking.
__global__ __launch_bounds__(256) void k_part(const int* __restrict__ ei,
                                              const float* __restrict__ ew,
                                              int* __restrict__ bfill,
                                              uint2* __restrict__ stg,
                                              int E, int nbuck, int cap) {
    __shared__ int lcnt[512];
    __shared__ int lbase[512];
    int tid = threadIdx.x;
    for (int i = tid; i < nbuck; i += 256) lcnt[i] = 0;
    __syncthreads();
    bool is64 = (ei[1] == 0) && (ei[3] == 0) && (ei[5] == 0) && (ei[7] == 0);
    int e0 = blockIdx.x * 2048;
    uint pack[8]; uint wb[8]; int bkt[8]; int rank[8];
    for (int u = 0; u < 8; u++) {
        int e = e0 + u * 256 + tid;
        bkt[u] = -1;
        if (e < E) {
            int s, d;
            if (is64) { s = ei[2 * e]; d = ei[2 * (E + e)]; }
            else      { s = ei[e];     d = ei[E + e]; }
            bkt[u] = d >> BSHIFT;
            pack[u] = ((uint)(d & (BNODES - 1)) << SRCBITS) | (uint)s;
            wb[u] = __float_as_uint(ew[e]);
            rank[u] = atomicAdd(&lcnt[bkt[u]], 1);
        }
    }
    __syncthreads();
    for (int i = tid; i < nbuck; i += 256)
        lbase[i] = lcnt[i] ? atomicAdd(&bfill[i], lcnt[i]) : 0;
    __syncthreads();
    for (int u = 0; u < 8; u++)
        if (bkt[u] >= 0)
            stg[(size_t)bkt[u] * cap + lbase[bkt[u]] + rank[u]] =
                make_uint2(pack[u], wb[u]);
}

// Tiny scan over bucket totals; also rowptr[N] = E.
__global__ void k_bscan(const int* __restrict__ bfill, int* __restrict__ cvbase,
                        int* __restrict__ rowptr, int nbuck, int N, int E) {
    if (threadIdx.x == 0 && blockIdx.x == 0) {
        int run = 0;
        for (int i = 0; i < nbuck; i++) { cvbase[i] = run; run += bfill[i]; }
        rowptr[N] = E;
    }
}

// Phase 2: one 512-thread block per 256-node bucket. LDS count -> scan ->
// ranked scatter into the bucket's private ~32KB cv window (single L2 owner).
// Fused: rowptr emission + deg/dis/p.
__global__ __launch_bounds__(512) void k_fine(const uint2* __restrict__ stg,
                                              const int* __restrict__ bfill,
                                              const int* __restrict__ cvbase,
                                              const float* __restrict__ x,
                                              float* __restrict__ dis,
                                              float* __restrict__ p,
                                              int* __restrict__ rowptr,
                                              int2* __restrict__ cv,
                                              int cap, int N) {
    __shared__ int cnt_l[BNODES];
    __shared__ int base_l[BNODES];
    __shared__ float degf[BNODES];
    __shared__ int wsum[4];
    int b = blockIdx.x, tid = threadIdx.x;
    int n = bfill[b];
    int cb = cvbase[b];
    const uint2* s = stg + (size_t)b * cap;
    if (tid < BNODES) { cnt_l[tid] = 0; degf[tid] = 1.0f; }
    __syncthreads();
    for (int i = tid; i < n; i += 512)
        atomicAdd(&cnt_l[s[i].x >> SRCBITS], 1);
    __syncthreads();
    int lane = tid & 63, wv = tid >> 6;
    int a = 0;
    if (tid < BNODES) { a = cnt_l[tid]; cnt_l[tid] = 0; }  // reuse as fill ctr
    int v = a;
    for (int off = 1; off < 64; off <<= 1) {
        int u = __shfl_up(v, off);
        if (lane >= off) v += u;
    }
    if (wv < 4 && lane == 63) wsum[wv] = v;
    __syncthreads();
    if (tid < BNODES) {
        int wpre = 0;
        for (int k = 0; k < wv; k++) wpre += wsum[k];
        base_l[tid] = v + wpre - a;
    }
    __syncthreads();
    for (int i = tid; i < n; i += 512) {
        uint2 r = s[i];
        int dl = r.x >> SRCBITS;
        int src = (int)(r.x & ((1u << SRCBITS) - 1));
        int pos = cb + base_l[dl] + atomicAdd(&cnt_l[dl], 1);
        cv[pos] = make_int2(src, (int)r.y);
        atomicAdd(&degf[dl], __uint_as_float(r.y));
    }
    __syncthreads();
    int gid = (b << BSHIFT) + tid;
    if (tid < BNODES && gid < N) {
        rowptr[gid] = cb + base_l[tid];
        float r = rsqrtf(degf[tid]);
        dis[gid] = r;
        p[gid] = r * x[gid];
    }
}

// Pre-transpose weights to bf16 chunk layout Bt[(k>>3)*NCOLS*8 + n*8 + (k&7)].
__global__ void k_prepB(const float* __restrict__ W2, const float* __restrict__ Wl1,
                        ushort* __restrict__ Bt1, ushort* __restrict__ Bt2) {
    int o = blockIdx.x * blockDim.x + threadIdx.x;
    if (o >= 32768) return;
    {   // Bt1: K=128, NCOLS=256
        int k0 = o & 7, n = (o >> 3) & 255, k8 = o >> 11;
        Bt1[o] = f2bf(W2[(size_t)(k8 * 8 + k0) * 256 + n]);
    }
    {   // Bt2: K=256, NCOLS=128
        int k0 = o & 7, n = (o >> 3) & 127, k8 = o >> 10;
        Bt2[o] = f2bf(Wl1[(size_t)(k8 * 8 + k0) * 128 + n]);
    }
}

// Quarter-wave per node: q = sum(val*p[col]); t = dis*(q+p); tp = (t, dis).
__global__ __launch_bounds__(256) void k_q(const int* __restrict__ rowptr,
                                           const int2* __restrict__ cv,
                                           const float* __restrict__ dis,
                                           const float* __restrict__ p,
                                           float2* __restrict__ tp, int N) {
    int gid = blockIdx.x * blockDim.x + threadIdx.x;
    int wid = gid >> 4;
    int sl = threadIdx.x & 15;
    if (wid >= N) return;
    int beg = rowptr[wid], end = rowptr[wid + 1];
    float s = 0.0f;
    for (int i = beg + sl; i < end; i += 16) {
        int2 pr = cv[i];
        s += __int_as_float(pr.y) * p[pr.x];
    }
    s += __shfl_xor(s, 1);
    s += __shfl_xor(s, 2);
    s += __shfl_xor(s, 4);
    s += __shfl_xor(s, 8);
    if (sl == 0) {
        float r = dis[wid];
        tp[wid] = make_float2(r * (s + p[wid]), r);
    }
}

// Fused aggregate + MLP. Wave-private throughout (no barriers):
//  phase 1: wave aggregates its 32 rows (rank-1 reconstruction from tp) into
//           a bf16 LDS tile zt (stride 68: balanced banks, 16B aligned).
//  phase 2: MFMA MLP (GEMM1 -> per-wave C->A staging -> GEMM2 -> wl2 dot).
__global__ __launch_bounds__(256) void k_zmlp(const int* __restrict__ rowptr,
                                              const int2* __restrict__ cv,
                                              const float2* __restrict__ tp,
                                              const float* __restrict__ W1,
                                              const float* __restrict__ b1,
                                              const ushort* __restrict__ Bt1,
                                              const ushort* __restrict__ Bt2,
                                              const float* __restrict__ b2,
                                              const float* __restrict__ bl1,
                                              const float* __restrict__ wl2,
                                              const float* __restrict__ bl2,
                                              float* __restrict__ out, int M) {
    __shared__ uint zt[4][32][68];     // 34.8KB: wave-private z tiles (bf16x2)
    __shared__ ushort st[4][32][40];   // 10KB: per-wave C->A staging
    int tid = threadIdx.x;
    int wv = tid >> 6, lane = tid & 63;
    int l15 = lane & 15, quad = lane >> 4;
    int row0 = blockIdx.x * 128 + wv * 32;
    float2 w1 = *(const float2*)(W1 + lane * 2);
    float2 bb1 = *(const float2*)(b1 + lane * 2);

    // phase 1: aggregate 32 rows
    for (int i = 0; i < 32; i++) {
        int r = row0 + i;
        uint zv = 0;
        if (r < M) {
            int beg = rowptr[r], end = rowptr[r + 1];
            float ax = 0.0f, ay = 0.0f;
            for (int base = beg; base < end; base += 64) {
                int eidx = base + lane;
                int cs = 0; float wvv = 0.0f;
                if (eidx < end) {
                    int2 pr = cv[eidx];
                    cs = pr.x;
                    wvv = __int_as_float(pr.y);
                }
                float2 tps = tp[cs];      // 8B gather, L2-resident (800 KB)
                float wd = wvv * tps.y;
                float tt = tps.x;
                int m = min(64, end - base);
                for (int j = 0; j < m; j++) {
                    float wdj = __shfl(wd, j);
                    float tj  = __shfl(tt, j);
                    ax = fmaf(wdj, fmaxf(fmaf(tj, w1.x, bb1.x), 0.0f), ax);
                    ay = fmaf(wdj, fmaxf(fmaf(tj, w1.y, bb1.y), 0.0f), ay);
                }
            }
            float2 tpd = tp[r];
            float rd = tpd.y;
            float s0 = rd * fmaxf(fmaf(tpd.x, w1.x, bb1.x), 0.0f);
            float s1 = rd * fmaxf(fmaf(tpd.x, w1.y, bb1.y), 0.0f);
            zv = packbf(rd * (ax + s0), rd * (ay + s1));
        }
        zt[wv][i][lane] = zv;
    }
    // no __syncthreads: zt/st tiles are wave-private; compiler orders LDS deps

    // phase 2: MLP. A1-frags from the LDS z tile.
    bf8_t a1[2][4];
    for (int kc = 0; kc < 4; kc++) {
        a1[0][kc] = *(const bf8_t*)((const ushort*)&zt[wv][l15][kc * 16 + quad * 4]);
        a1[1][kc] = *(const bf8_t*)((const ushort*)&zt[wv][16 + l15][kc * 16 + quad * 4]);
    }
    f32x4 acc2[2][8];
    for (int i = 0; i < 2; i++)
        for (int j = 0; j < 8; j++) acc2[i][j] = (f32x4){0.f, 0.f, 0.f, 0.f};

    for (int c = 0; c < 8; c++) {         // 32-col chunk of h2 == 32-k of GEMM2
        f32x4 acc1[2][2];
        for (int i = 0; i < 2; i++)
            for (int j = 0; j < 2; j++) acc1[i][j] = (f32x4){0.f, 0.f, 0.f, 0.f};
        for (int kc = 0; kc < 4; kc++)
            for (int nt = 0; nt < 2; nt++) {
                bf8_t b = *(const bf8_t*)(Bt1 +
                    ((size_t)(kc * 4 + quad) * 256 + c * 32 + nt * 16 + l15) * 8);
                acc1[0][nt] = __builtin_amdgcn_mfma_f32_16x16x32_bf16(a1[0][kc], b, acc1[0][nt], 0, 0, 0);
                acc1[1][nt] = __builtin_amdgcn_mfma_f32_16x16x32_bf16(a1[1][kc], b, acc1[1][nt], 0, 0, 0);
            }
        for (int nt = 0; nt < 2; nt++) {
            float bb = b2[c * 32 + nt * 16 + l15];
            for (int mt = 0; mt < 2; mt++)
                for (int rg = 0; rg < 4; rg++)
                    st[wv][mt * 16 + quad * 4 + rg][nt * 16 + l15] =
                        f2bf(fmaxf(acc1[mt][nt][rg] + bb, 0.f));
        }
        bf8_t a2_0 = *(const bf8_t*)&st[wv][l15][quad * 8];
        bf8_t a2_1 = *(const bf8_t*)&st[wv][16 + l15][quad * 8];
        for (int nt2 = 0; nt2 < 8; nt2++) {
            bf8_t b = *(const bf8_t*)(Bt2 +
                ((size_t)(c * 4 + quad) * 128 + nt2 * 16 + l15) * 8);
            acc2[0][nt2] = __builtin_amdgcn_mfma_f32_16x16x32_bf16(a2_0, b, acc2[0][nt2], 0, 0, 0);
            acc2[1][nt2] = __builtin_amdgcn_mfma_f32_16x16x32_bf16(a2_1, b, acc2[1][nt2], 0, 0, 0);
        }
    }
    float rs[2][4] = {};
    for (int nt2 = 0; nt2 < 8; nt2++) {
        int col = nt2 * 16 + l15;
        float bb = bl1[col], ww = wl2[col];
        for (int mt = 0; mt < 2; mt++)
            for (int rg = 0; rg < 4; rg++)
                rs[mt][rg] += fmaxf(acc2[mt][nt2][rg] + bb, 0.f) * ww;
    }
    float base = bl2[0];
    for (int mt = 0; mt < 2; mt++)
        for (int rg = 0; rg < 4; rg++) {
            float s = rs[mt][rg];
            s += __shfl_xor(s, 1);
            s += __shfl_xor(s, 2);
            s += __shfl_xor(s, 4);
            s += __shfl_xor(s, 8);
            int row = row0 + mt * 16 + quad * 4 + rg;
            if (l15 == 0 && row < M) out[row] = s + base;
        }
}

extern "C" void kernel_launch(void* const* d_in, const int* in_sizes, int n_in,
                              void* d_out, int out_size, void* d_ws, size_t ws_size,
                              hipStream_t stream) {
    const float* x   = (const float*)d_in[0];
    const int*   ei  = (const int*)d_in[1];
    const float* ew  = (const float*)d_in[2];
    const float* W1  = (const float*)d_in[3];
    const float* b1  = (const float*)d_in[4];
    const float* W2  = (const float*)d_in[5];
    const float* b2  = (const float*)d_in[6];
    const float* Wl1 = (const float*)d_in[7];
    const float* bl1 = (const float*)d_in[8];
    const float* Wl2 = (const float*)d_in[9];
    const float* bl2 = (const float*)d_in[10];
    float* out = (float*)d_out;
    const int N = in_sizes[0];
    const int E = in_sizes[2];

    const int nbuck = (N + BNODES - 1) >> BSHIFT;             // 391
    const int cap = ((E / nbuck) * 5) / 4 + 1024;             // +~32 sigma slack

    char* w = (char*)d_ws;
    size_t off = 0;
    auto alloc = [&](size_t bytes) -> void* {
        void* p = w + off;
        off = align256(off + bytes);
        return p;
    };
    float2* tp     = (float2*)alloc((size_t)N * 8);         // (t, dis)
    float*  dis    = (float*)alloc((size_t)N * 4);
    float*  p_     = (float*)alloc((size_t)N * 4);
    int*    rowptr = (int*)alloc((size_t)(N + 1) * 4);
    int2*   cv     = (int2*)alloc((size_t)E * 8);
    uint2*  stg    = (uint2*)alloc((size_t)nbuck * cap * 8);
    int*    bfill  = (int*)alloc(512 * 4);
    int*    cvbase = (int*)alloc(512 * 4);
    ushort* Bt1    = (ushort*)alloc(32768 * 2);
    ushort* Bt2    = (ushort*)alloc(32768 * 2);

    hipMemsetAsync(bfill, 0, 512 * 4, stream);
    k_part<<<(E + 2047) / 2048, 256, 0, stream>>>(ei, ew, bfill, stg, E, nbuck, cap);
    k_bscan<<<1, 64, 0, stream>>>(bfill, cvbase, rowptr, nbuck, N, E);
    k_fine<<<nbuck, 512, 0, stream>>>(stg, bfill, cvbase, x, dis, p_, rowptr, cv, cap, N);
    k_prepB<<<128, 256, 0, stream>>>(W2, Wl1, Bt1, Bt2);
    k_q<<<(N * 16 + 255) / 256, 256, 0, stream>>>(rowptr, cv, dis, p_, tp, N);
    k_zmlp<<<(N + 127) / 128, 256, 0, stream>>>(rowptr, cv, tp, W1, b1, Bt1, Bt2,
                                                b2, bl1, Wl2, bl2, out, N);
}

// Round 9
// 245.337 us; speedup vs baseline: 1.2496x; 1.2496x over previous
//
#include <hip/hip_runtime.h>

// GCN on MI355X — round 9: revert the agg+MLP fusion (r8 regression), keep
// the parallelized bucket sort.
//  - r8 lesson: k_zmlp's wave-serial 32-row aggregation at 16% occupancy
//    (45KB LDS) exposes the tp-gather latency; separate k_agg has 100K
//    independent waves and hides it. Fusion saved only ~8us of z traffic.
//  - Keep from r8: 391 buckets x 256 nodes, 512-thread k_fine (occupancy fix:
//    51 -> ~15us).
//  - k_agg (wave/node, rank-1 reconstruction) + k_mlp (global z) from r7.

#define HD 128
#define HD2 256
#define BSHIFT 8             // 256 nodes per bucket -> 391 buckets
#define BNODES 256
#define SRCBITS 17           // N=100000 < 2^17

typedef __attribute__((ext_vector_type(8))) short bf8_t;   // 8 x bf16 (4 VGPR)
typedef __attribute__((ext_vector_type(4))) float f32x4;

static inline size_t align256(size_t x) { return (x + 255) & ~(size_t)255; }

__device__ inline ushort f2bf(float f) {            // RNE f32 -> bf16
    uint u = __float_as_uint(f);
    uint r = u + 0x7fffu + ((u >> 16) & 1u);
    return (ushort)(r >> 16);
}
__device__ inline uint packbf(float a, float b) {
    return (uint)f2bf(a) | ((uint)f2bf(b) << 16);
}

// Phase 1: stream edges once, partition into 391 dst-buckets via LDS ranking.
__global__ __launch_bounds__(256) void k_part(const int* __restrict__ ei,
                                              const float* __restrict__ ew,
                                              int* __restrict__ bfill,
                                              uint2* __restrict__ stg,
                                              int E, int nbuck, int cap) {
    __shared__ int lcnt[512];
    __shared__ int lbase[512];
    int tid = threadIdx.x;
    for (int i = tid; i < nbuck; i += 256) lcnt[i] = 0;
    __syncthreads();
    bool is64 = (ei[1] == 0) && (ei[3] == 0) && (ei[5] == 0) && (ei[7] == 0);
    int e0 = blockIdx.x * 2048;
    uint pack[8]; uint wb[8]; int bkt[8]; int rank[8];
    for (int u = 0; u < 8; u++) {
        int e = e0 + u * 256 + tid;
        bkt[u] = -1;
        if (e < E) {
            int s, d;
            if (is64) { s = ei[2 * e]; d = ei[2 * (E + e)]; }
            else      { s = ei[e];     d = ei[E + e]; }
            bkt[u] = d >> BSHIFT;
            pack[u] = ((uint)(d & (BNODES - 1)) << SRCBITS) | (uint)s;
            wb[u] = __float_as_uint(ew[e]);
            rank[u] = atomicAdd(&lcnt[bkt[u]], 1);
        }
    }
    __syncthreads();
    for (int i = tid; i < nbuck; i += 256)
        lbase[i] = lcnt[i] ? atomicAdd(&bfill[i], lcnt[i]) : 0;
    __syncthreads();
    for (int u = 0; u < 8; u++)
        if (bkt[u] >= 0)
            stg[(size_t)bkt[u] * cap + lbase[bkt[u]] + rank[u]] =
                make_uint2(pack[u], wb[u]);
}

// Tiny scan over bucket totals; also rowptr[N] = E.
__global__ void k_bscan(const int* __restrict__ bfill, int* __restrict__ cvbase,
                        int* __restrict__ rowptr, int nbuck, int N, int E) {
    if (threadIdx.x == 0 && blockIdx.x == 0) {
        int run = 0;
        for (int i = 0; i < nbuck; i++) { cvbase[i] = run; run += bfill[i]; }
        rowptr[N] = E;
    }
}

// Phase 2: one 512-thread block per 256-node bucket. LDS count -> scan ->
// ranked scatter into the bucket's private ~32KB cv window (single L2 owner).
// Fused: rowptr emission + deg/dis/p.
__global__ __launch_bounds__(512) void k_fine(const uint2* __restrict__ stg,
                                              const int* __restrict__ bfill,
                                              const int* __restrict__ cvbase,
                                              const float* __restrict__ x,
                                              float* __restrict__ dis,
                                              float* __restrict__ p,
                                              int* __restrict__ rowptr,
                                              int2* __restrict__ cv,
                                              int cap, int N) {
    __shared__ int cnt_l[BNODES];
    __shared__ int base_l[BNODES];
    __shared__ float degf[BNODES];
    __shared__ int wsum[4];
    int b = blockIdx.x, tid = threadIdx.x;
    int n = bfill[b];
    int cb = cvbase[b];
    const uint2* s = stg + (size_t)b * cap;
    if (tid < BNODES) { cnt_l[tid] = 0; degf[tid] = 1.0f; }
    __syncthreads();
    for (int i = tid; i < n; i += 512)
        atomicAdd(&cnt_l[s[i].x >> SRCBITS], 1);
    __syncthreads();
    int lane = tid & 63, wv = tid >> 6;
    int a = 0;
    if (tid < BNODES) { a = cnt_l[tid]; cnt_l[tid] = 0; }  // reuse as fill ctr
    int v = a;
    for (int off = 1; off < 64; off <<= 1) {
        int u = __shfl_up(v, off);
        if (lane >= off) v += u;
    }
    if (wv < 4 && lane == 63) wsum[wv] = v;
    __syncthreads();
    if (tid < BNODES) {
        int wpre = 0;
        for (int k = 0; k < wv; k++) wpre += wsum[k];
        base_l[tid] = v + wpre - a;
    }
    __syncthreads();
    for (int i = tid; i < n; i += 512) {
        uint2 r = s[i];
        int dl = r.x >> SRCBITS;
        int src = (int)(r.x & ((1u << SRCBITS) - 1));
        int pos = cb + base_l[dl] + atomicAdd(&cnt_l[dl], 1);
        cv[pos] = make_int2(src, (int)r.y);
        atomicAdd(&degf[dl], __uint_as_float(r.y));
    }
    __syncthreads();
    int gid = (b << BSHIFT) + tid;
    if (tid < BNODES && gid < N) {
        rowptr[gid] = cb + base_l[tid];
        float r = rsqrtf(degf[tid]);
        dis[gid] = r;
        p[gid] = r * x[gid];
    }
}

// Pre-transpose weights to bf16 chunk layout Bt[(k>>3)*NCOLS*8 + n*8 + (k&7)].
__global__ void k_prepB(const float* __restrict__ W2, const float* __restrict__ Wl1,
                        ushort* __restrict__ Bt1, ushort* __restrict__ Bt2) {
    int o = blockIdx.x * blockDim.x + threadIdx.x;
    if (o >= 32768) return;
    {   // Bt1: K=128, NCOLS=256
        int k0 = o & 7, n = (o >> 3) & 255, k8 = o >> 11;
        Bt1[o] = f2bf(W2[(size_t)(k8 * 8 + k0) * 256 + n]);
    }
    {   // Bt2: K=256, NCOLS=128
        int k0 = o & 7, n = (o >> 3) & 127, k8 = o >> 10;
        Bt2[o] = f2bf(Wl1[(size_t)(k8 * 8 + k0) * 128 + n]);
    }
}

// Quarter-wave per node: q = sum(val*p[col]); t = dis*(q+p); tp = (t, dis).
__global__ __launch_bounds__(256) void k_q(const int* __restrict__ rowptr,
                                           const int2* __restrict__ cv,
                                           const float* __restrict__ dis,
                                           const float* __restrict__ p,
                                           float2* __restrict__ tp, int N) {
    int gid = blockIdx.x * blockDim.x + threadIdx.x;
    int wid = gid >> 4;
    int sl = threadIdx.x & 15;
    if (wid >= N) return;
    int beg = rowptr[wid], end = rowptr[wid + 1];
    float s = 0.0f;
    for (int i = beg + sl; i < end; i += 16) {
        int2 pr = cv[i];
        s += __int_as_float(pr.y) * p[pr.x];
    }
    s += __shfl_xor(s, 1);
    s += __shfl_xor(s, 2);
    s += __shfl_xor(s, 4);
    s += __shfl_xor(s, 8);
    if (sl == 0) {
        float r = dis[wid];
        tp[wid] = make_float2(r * (s + p[wid]), r);
    }
}

// Wave per node, rank-1 reconstruction:
// z[d][:] = dis_d * ( sum_e w_e*dis_s*relu(t_s*W1[:]+b1[:]) + dis_d*relu(t_d*W1[:]+b1[:]) )
// Per 64-edge batch: 2 wave-loads (cv batch + tp gather), then pure VALU/shfl.
__global__ __launch_bounds__(256) void k_agg(const int* __restrict__ rowptr,
                                             const int2* __restrict__ cv,
                                             const float2* __restrict__ tp,
                                             const float* __restrict__ W1,
                                             const float* __restrict__ b1,
                                             uint* __restrict__ z, int N) {
    int wid = (blockIdx.x * blockDim.x + threadIdx.x) >> 6;
    int lane = threadIdx.x & 63;
    if (wid >= N) return;
    float2 w1 = *(const float2*)(W1 + lane * 2);
    float2 bb = *(const float2*)(b1 + lane * 2);
    int beg = rowptr[wid], end = rowptr[wid + 1];
    float ax = 0.0f, ay = 0.0f;
    for (int base = beg; base < end; base += 64) {
        int eidx = base + lane;
        int cs = 0;
        float wv = 0.0f;
        if (eidx < end) {
            int2 pr = cv[eidx];
            cs = pr.x;
            wv = __int_as_float(pr.y);
        }
        float2 tps = tp[cs];           // 8B gather, L2-resident (800 KB array)
        float wd = wv * tps.y;         // w_e * dis_src
        float tt = tps.x;              // t_src
        int m = min(64, end - base);
        for (int j = 0; j < m; j++) {
            float wdj = __shfl(wd, j);
            float tj  = __shfl(tt, j);
            float f0 = fmaxf(fmaf(tj, w1.x, bb.x), 0.0f);
            float f1 = fmaxf(fmaf(tj, w1.y, bb.y), 0.0f);
            ax = fmaf(wdj, f0, ax);
            ay = fmaf(wdj, f1, ay);
        }
    }
    float2 tpd = tp[wid];
    float rd = tpd.y;
    float s0 = rd * fmaxf(fmaf(tpd.x, w1.x, bb.x), 0.0f);   // g1[d] self term
    float s1 = rd * fmaxf(fmaf(tpd.x, w1.y, bb.y), 0.0f);
    z[(size_t)wid * 64 + lane] = packbf(rd * (ax + s0), rd * (ay + s1));
}

// Fused MLP: out[i] = relu(relu(z[i]@W2+b2)@Wl1+bl1) . wl2 + bl2.
// 4 independent waves/block, 32 rows each. h2 lives only in regs + per-wave LDS.
__global__ __launch_bounds__(256) void k_mlp(const ushort* __restrict__ A,    // z bf16 [N][128]
                                             const ushort* __restrict__ Bt1,  // [16][256][8]
                                             const ushort* __restrict__ Bt2,  // [32][128][8]
                                             const float* __restrict__ b2,
                                             const float* __restrict__ bl1,
                                             const float* __restrict__ wl2,
                                             const float* __restrict__ bl2,
                                             float* __restrict__ out, int M) {
    __shared__ ushort st[4][32][40];   // per-wave C->A staging; 80B row stride
    int tid = threadIdx.x;
    int wv = tid >> 6, lane = tid & 63;
    int l15 = lane & 15, quad = lane >> 4;
    int row0 = blockIdx.x * 128 + wv * 32;
    int r0 = row0 + l15;      r0 = r0 < M ? r0 : M - 1;   // clamp; stores guarded
    int r1 = row0 + 16 + l15; r1 = r1 < M ? r1 : M - 1;

    bf8_t a1[2][4];                       // all A1 frags resident (32 VGPR)
    for (int kc = 0; kc < 4; kc++) {
        a1[0][kc] = *(const bf8_t*)(A + (size_t)r0 * 128 + kc * 32 + quad * 8);
        a1[1][kc] = *(const bf8_t*)(A + (size_t)r1 * 128 + kc * 32 + quad * 8);
    }
    f32x4 acc2[2][8];
    for (int i = 0; i < 2; i++)
        for (int j = 0; j < 8; j++) acc2[i][j] = (f32x4){0.f, 0.f, 0.f, 0.f};

    for (int c = 0; c < 8; c++) {         // 32-col chunk of h2 == 32-k of GEMM2
        f32x4 acc1[2][2];
        for (int i = 0; i < 2; i++)
            for (int j = 0; j < 2; j++) acc1[i][j] = (f32x4){0.f, 0.f, 0.f, 0.f};
        for (int kc = 0; kc < 4; kc++)
            for (int nt = 0; nt < 2; nt++) {
                bf8_t b = *(const bf8_t*)(Bt1 +
                    ((size_t)(kc * 4 + quad) * 256 + c * 32 + nt * 16 + l15) * 8);
                acc1[0][nt] = __builtin_amdgcn_mfma_f32_16x16x32_bf16(a1[0][kc], b, acc1[0][nt], 0, 0, 0);
                acc1[1][nt] = __builtin_amdgcn_mfma_f32_16x16x32_bf16(a1[1][kc], b, acc1[1][nt], 0, 0, 0);
            }
        for (int nt = 0; nt < 2; nt++) {
            float bb = b2[c * 32 + nt * 16 + l15];
            for (int mt = 0; mt < 2; mt++)
                for (int rg = 0; rg < 4; rg++)
                    st[wv][mt * 16 + quad * 4 + rg][nt * 16 + l15] =
                        f2bf(fmaxf(acc1[mt][nt][rg] + bb, 0.f));
        }
        bf8_t a2_0 = *(const bf8_t*)&st[wv][l15][quad * 8];
        bf8_t a2_1 = *(const bf8_t*)&st[wv][16 + l15][quad * 8];
        for (int nt2 = 0; nt2 < 8; nt2++) {
            bf8_t b = *(const bf8_t*)(Bt2 +
                ((size_t)(c * 4 + quad) * 128 + nt2 * 16 + l15) * 8);
            acc2[0][nt2] = __builtin_amdgcn_mfma_f32_16x16x32_bf16(a2_0, b, acc2[0][nt2], 0, 0, 0);
            acc2[1][nt2] = __builtin_amdgcn_mfma_f32_16x16x32_bf16(a2_1, b, acc2[1][nt2], 0, 0, 0);
        }
    }
    float rs[2][4] = {};
    for (int nt2 = 0; nt2 < 8; nt2++) {
        int col = nt2 * 16 + l15;
        float bb = bl1[col], ww = wl2[col];
        for (int mt = 0; mt < 2; mt++)
            for (int rg = 0; rg < 4; rg++)
                rs[mt][rg] += fmaxf(acc2[mt][nt2][rg] + bb, 0.f) * ww;
    }
    float base = bl2[0];
    for (int mt = 0; mt < 2; mt++)
        for (int rg = 0; rg < 4; rg++) {
            float s = rs[mt][rg];
            s += __shfl_xor(s, 1);
            s += __shfl_xor(s, 2);
            s += __shfl_xor(s, 4);
            s += __shfl_xor(s, 8);
            int row = row0 + mt * 16 + quad * 4 + rg;
            if (l15 == 0 && row < M) out[row] = s + base;
        }
}

extern "C" void kernel_launch(void* const* d_in, const int* in_sizes, int n_in,
                              void* d_out, int out_size, void* d_ws, size_t ws_size,
                              hipStream_t stream) {
    const float* x   = (const float*)d_in[0];
    const int*   ei  = (const int*)d_in[1];
    const float* ew  = (const float*)d_in[2];
    const float* W1  = (const float*)d_in[3];
    const float* b1  = (const float*)d_in[4];
    const float* W2  = (const float*)d_in[5];
    const float* b2  = (const float*)d_in[6];
    const float* Wl1 = (const float*)d_in[7];
    const float* bl1 = (const float*)d_in[8];
    const float* Wl2 = (const float*)d_in[9];
    const float* bl2 = (const float*)d_in[10];
    float* out = (float*)d_out;
    const int N = in_sizes[0];
    const int E = in_sizes[2];

    const int nbuck = (N + BNODES - 1) >> BSHIFT;             // 391
    const int cap = ((E / nbuck) * 5) / 4 + 1024;             // +~32 sigma slack

    char* w = (char*)d_ws;
    size_t off = 0;
    auto alloc = [&](size_t bytes) -> void* {
        void* p = w + off;
        off = align256(off + bytes);
        return p;
    };
    uint*   z      = (uint*)alloc((size_t)N * 64 * 4);      // bf16 [N][128]
    float2* tp     = (float2*)alloc((size_t)N * 8);         // (t, dis)
    float*  dis    = (float*)alloc((size_t)N * 4);
    float*  p_     = (float*)alloc((size_t)N * 4);
    int*    rowptr = (int*)alloc((size_t)(N + 1) * 4);
    int2*   cv     = (int2*)alloc((size_t)E * 8);
    uint2*  stg    = (uint2*)alloc((size_t)nbuck * cap * 8);
    int*    bfill  = (int*)alloc(512 * 4);
    int*    cvbase = (int*)alloc(512 * 4);
    ushort* Bt1    = (ushort*)alloc(32768 * 2);
    ushort* Bt2    = (ushort*)alloc(32768 * 2);

    hipMemsetAsync(bfill, 0, 512 * 4, stream);
    k_part<<<(E + 2047) / 2048, 256, 0, stream>>>(ei, ew, bfill, stg, E, nbuck, cap);
    k_bscan<<<1, 64, 0, stream>>>(bfill, cvbase, rowptr, nbuck, N, E);
    k_fine<<<nbuck, 512, 0, stream>>>(stg, bfill, cvbase, x, dis, p_, rowptr, cv, cap, N);
    k_prepB<<<128, 256, 0, stream>>>(W2, Wl1, Bt1, Bt2);
    k_q<<<(N * 16 + 255) / 256, 256, 0, stream>>>(rowptr, cv, dis, p_, tp, N);
    k_agg<<<(N + 3) / 4, 256, 0, stream>>>(rowptr, cv, tp, W1, b1, z, N);
    k_mlp<<<(N + 127) / 128, 256, 0, stream>>>((const ushort*)z, Bt1, Bt2,
                                               b2, bl1, Wl2, bl2, out, N);
}

// Round 10
// 213.012 us; speedup vs baseline: 1.4393x; 1.1518x over previous
//
#include <hip/hip_runtime.h>

// GCN on MI355X — round 10: fix two latency sinks found by r9 arithmetic.
//  1) k_bscan was a SINGLE-THREAD serial loop over 391 buckets (~30us of
//     dependent global round-trips). Now: one-block parallel wave-scan (~2us).
//  2) k_agg inner loop: replace 2 shfl-broadcasts/edge (ds_bpermute +
//     per-iter waitcnt serialization) with a wave-private LDS edge buffer
//     read via ds_read_b128 broadcast, 2 edges per iteration, unconditional
//     (padding slots are (0,0) -> contribute 0 through relu/fma).
//  Everything else (bucket sort, rank-1 reconstruction, fused MLP) from r9.

#define HD 128
#define HD2 256
#define BSHIFT 8             // 256 nodes per bucket -> 391 buckets
#define BNODES 256
#define SRCBITS 17           // N=100000 < 2^17

typedef __attribute__((ext_vector_type(8))) short bf8_t;   // 8 x bf16 (4 VGPR)
typedef __attribute__((ext_vector_type(4))) float f32x4;

static inline size_t align256(size_t x) { return (x + 255) & ~(size_t)255; }

__device__ inline ushort f2bf(float f) {            // RNE f32 -> bf16
    uint u = __float_as_uint(f);
    uint r = u + 0x7fffu + ((u >> 16) & 1u);
    return (ushort)(r >> 16);
}
__device__ inline uint packbf(float a, float b) {
    return (uint)f2bf(a) | ((uint)f2bf(b) << 16);
}

// Phase 1: stream edges once, partition into 391 dst-buckets via LDS ranking.
__global__ __launch_bounds__(256) void k_part(const int* __restrict__ ei,
                                              const float* __restrict__ ew,
                                              int* __restrict__ bfill,
                                              uint2* __restrict__ stg,
                                              int E, int nbuck, int cap) {
    __shared__ int lcnt[512];
    __shared__ int lbase[512];
    int tid = threadIdx.x;
    for (int i = tid; i < nbuck; i += 256) lcnt[i] = 0;
    __syncthreads();
    bool is64 = (ei[1] == 0) && (ei[3] == 0) && (ei[5] == 0) && (ei[7] == 0);
    int e0 = blockIdx.x * 2048;
    uint pack[8]; uint wb[8]; int bkt[8]; int rank[8];
    for (int u = 0; u < 8; u++) {
        int e = e0 + u * 256 + tid;
        bkt[u] = -1;
        if (e < E) {
            int s, d;
            if (is64) { s = ei[2 * e]; d = ei[2 * (E + e)]; }
            else      { s = ei[e];     d = ei[E + e]; }
            bkt[u] = d >> BSHIFT;
            pack[u] = ((uint)(d & (BNODES - 1)) << SRCBITS) | (uint)s;
            wb[u] = __float_as_uint(ew[e]);
            rank[u] = atomicAdd(&lcnt[bkt[u]], 1);
        }
    }
    __syncthreads();
    for (int i = tid; i < nbuck; i += 256)
        lbase[i] = lcnt[i] ? atomicAdd(&bfill[i], lcnt[i]) : 0;
    __syncthreads();
    for (int u = 0; u < 8; u++)
        if (bkt[u] >= 0)
            stg[(size_t)bkt[u] * cap + lbase[bkt[u]] + rank[u]] =
                make_uint2(pack[u], wb[u]);
}

// Parallel exclusive scan over bucket totals (one block); rowptr[N] = E.
__global__ __launch_bounds__(512) void k_bscan(const int* __restrict__ bfill,
                                               int* __restrict__ cvbase,
                                               int* __restrict__ rowptr,
                                               int nbuck, int N, int E) {
    __shared__ int ws[8];
    int tid = threadIdx.x;
    int lane = tid & 63, wvid = tid >> 6;
    int a = (tid < nbuck) ? bfill[tid] : 0;
    int v = a;
    for (int off = 1; off < 64; off <<= 1) {
        int u = __shfl_up(v, off);
        if (lane >= off) v += u;
    }
    if (lane == 63) ws[wvid] = v;
    __syncthreads();
    int wpre = 0;
    for (int k = 0; k < wvid; k++) wpre += ws[k];
    if (tid < nbuck) cvbase[tid] = v + wpre - a;
    if (tid == 0) rowptr[N] = E;
}

// Phase 2: one 512-thread block per 256-node bucket. LDS count -> scan ->
// ranked scatter into the bucket's private ~32KB cv window (single L2 owner).
// Fused: rowptr emission + deg/dis/p.
__global__ __launch_bounds__(512) void k_fine(const uint2* __restrict__ stg,
                                              const int* __restrict__ bfill,
                                              const int* __restrict__ cvbase,
                                              const float* __restrict__ x,
                                              float* __restrict__ dis,
                                              float* __restrict__ p,
                                              int* __restrict__ rowptr,
                                              int2* __restrict__ cv,
                                              int cap, int N) {
    __shared__ int cnt_l[BNODES];
    __shared__ int base_l[BNODES];
    __shared__ float degf[BNODES];
    __shared__ int wsum[4];
    int b = blockIdx.x, tid = threadIdx.x;
    int n = bfill[b];
    int cb = cvbase[b];
    const uint2* s = stg + (size_t)b * cap;
    if (tid < BNODES) { cnt_l[tid] = 0; degf[tid] = 1.0f; }
    __syncthreads();
    for (int i = tid; i < n; i += 512)
        atomicAdd(&cnt_l[s[i].x >> SRCBITS], 1);
    __syncthreads();
    int lane = tid & 63, wvid = tid >> 6;
    int a = 0;
    if (tid < BNODES) { a = cnt_l[tid]; cnt_l[tid] = 0; }  // reuse as fill ctr
    int v = a;
    for (int off = 1; off < 64; off <<= 1) {
        int u = __shfl_up(v, off);
        if (lane >= off) v += u;
    }
    if (wvid < 4 && lane == 63) wsum[wvid] = v;
    __syncthreads();
    if (tid < BNODES) {
        int wpre = 0;
        for (int k = 0; k < wvid; k++) wpre += wsum[k];
        base_l[tid] = v + wpre - a;
    }
    __syncthreads();
    for (int i = tid; i < n; i += 512) {
        uint2 r = s[i];
        int dl = r.x >> SRCBITS;
        int src = (int)(r.x & ((1u << SRCBITS) - 1));
        int pos = cb + base_l[dl] + atomicAdd(&cnt_l[dl], 1);
        cv[pos] = make_int2(src, (int)r.y);
        atomicAdd(&degf[dl], __uint_as_float(r.y));
    }
    __syncthreads();
    int gid = (b << BSHIFT) + tid;
    if (tid < BNODES && gid < N) {
        rowptr[gid] = cb + base_l[tid];
        float r = rsqrtf(degf[tid]);
        dis[gid] = r;
        p[gid] = r * x[gid];
    }
}

// Pre-transpose weights to bf16 chunk layout Bt[(k>>3)*NCOLS*8 + n*8 + (k&7)].
__global__ void k_prepB(const float* __restrict__ W2, const float* __restrict__ Wl1,
                        ushort* __restrict__ Bt1, ushort* __restrict__ Bt2) {
    int o = blockIdx.x * blockDim.x + threadIdx.x;
    if (o >= 32768) return;
    {   // Bt1: K=128, NCOLS=256
        int k0 = o & 7, n = (o >> 3) & 255, k8 = o >> 11;
        Bt1[o] = f2bf(W2[(size_t)(k8 * 8 + k0) * 256 + n]);
    }
    {   // Bt2: K=256, NCOLS=128
        int k0 = o & 7, n = (o >> 3) & 127, k8 = o >> 10;
        Bt2[o] = f2bf(Wl1[(size_t)(k8 * 8 + k0) * 128 + n]);
    }
}

// Quarter-wave per node: q = sum(val*p[col]); t = dis*(q+p); tp = (t, dis).
__global__ __launch_bounds__(256) void k_q(const int* __restrict__ rowptr,
                                           const int2* __restrict__ cv,
                                           const float* __restrict__ dis,
                                           const float* __restrict__ p,
                                           float2* __restrict__ tp, int N) {
    int gid = blockIdx.x * blockDim.x + threadIdx.x;
    int wid = gid >> 4;
    int sl = threadIdx.x & 15;
    if (wid >= N) return;
    int beg = rowptr[wid], end = rowptr[wid + 1];
    float s = 0.0f;
    for (int i = beg + sl; i < end; i += 16) {
        int2 pr = cv[i];
        s += __int_as_float(pr.y) * p[pr.x];
    }
    s += __shfl_xor(s, 1);
    s += __shfl_xor(s, 2);
    s += __shfl_xor(s, 4);
    s += __shfl_xor(s, 8);
    if (sl == 0) {
        float r = dis[wid];
        tp[wid] = make_float2(r * (s + p[wid]), r);
    }
}

// Wave per node, rank-1 reconstruction:
// z[d][:] = dis_d * ( sum_e w_e*dis_s*relu(t_s*W1[:]+b1[:]) + dis_d*relu(t_d*W1[:]+b1[:]) )
// Per 64-edge batch: stage (wd,t) to wave-private LDS, then broadcast-read
// 2 edges/iter via ds_read_b128. Padding slots are (0,0): relu(b1) is finite
// and wd=0 -> fma adds exactly 0, so the pair loop needs no guards.
__global__ __launch_bounds__(256) void k_agg(const int* __restrict__ rowptr,
                                             const int2* __restrict__ cv,
                                             const float2* __restrict__ tp,
                                             const float* __restrict__ W1,
                                             const float* __restrict__ b1,
                                             uint* __restrict__ z, int N) {
    __shared__ float4 eb[4][32];       // 2 KB: per-wave (wd,t) x64 edge slots
    int tid = threadIdx.x;
    int wvid = tid >> 6, lane = tid & 63;
    int wid = (blockIdx.x * blockDim.x + tid) >> 6;
    if (wid >= N) return;
    float2 w1 = *(const float2*)(W1 + lane * 2);
    float2 bb = *(const float2*)(b1 + lane * 2);
    int beg = rowptr[wid], end = rowptr[wid + 1];
    float ax = 0.0f, ay = 0.0f;
    for (int base = beg; base < end; base += 64) {
        int eidx = base + lane;
        float wd = 0.0f, tt = 0.0f;
        if (eidx < end) {
            int2 pr = cv[eidx];
            float2 tps = tp[pr.x];     // 8B gather, L2-resident (800 KB array)
            wd = __int_as_float(pr.y) * tps.y;   // w_e * dis_src
            tt = tps.x;                          // t_src
        }
        ((float2*)&eb[wvid][0])[lane] = make_float2(wd, tt);
        int m = min(64, end - base);
        const float4* ebp = &eb[wvid][0];
        int halves = (m + 1) >> 1;
        for (int u = 0; u < halves; u++) {
            float4 e2 = ebp[u];        // ds_read_b128 broadcast: 2 edges
            float f0 = fmaxf(fmaf(e2.y, w1.x, bb.x), 0.0f);
            float f1 = fmaxf(fmaf(e2.y, w1.y, bb.y), 0.0f);
            ax = fmaf(e2.x, f0, ax);
            ay = fmaf(e2.x, f1, ay);
            float g0 = fmaxf(fmaf(e2.w, w1.x, bb.x), 0.0f);
            float g1 = fmaxf(fmaf(e2.w, w1.y, bb.y), 0.0f);
            ax = fmaf(e2.z, g0, ax);
            ay = fmaf(e2.z, g1, ay);
        }
    }
    float2 tpd = tp[wid];
    float rd = tpd.y;
    float s0 = rd * fmaxf(fmaf(tpd.x, w1.x, bb.x), 0.0f);   // g1[d] self term
    float s1 = rd * fmaxf(fmaf(tpd.x, w1.y, bb.y), 0.0f);
    z[(size_t)wid * 64 + lane] = packbf(rd * (ax + s0), rd * (ay + s1));
}

// Fused MLP: out[i] = relu(relu(z[i]@W2+b2)@Wl1+bl1) . wl2 + bl2.
// 4 independent waves/block, 32 rows each. h2 lives only in regs + per-wave LDS.
__global__ __launch_bounds__(256) void k_mlp(const ushort* __restrict__ A,    // z bf16 [N][128]
                                             const ushort* __restrict__ Bt1,  // [16][256][8]
                                             const ushort* __restrict__ Bt2,  // [32][128][8]
                                             const float* __restrict__ b2,
                                             const float* __restrict__ bl1,
                                             const float* __restrict__ wl2,
                                             const float* __restrict__ bl2,
                                             float* __restrict__ out, int M) {
    __shared__ ushort st[4][32][40];   // per-wave C->A staging; 80B row stride
    int tid = threadIdx.x;
    int wv = tid >> 6, lane = tid & 63;
    int l15 = lane & 15, quad = lane >> 4;
    int row0 = blockIdx.x * 128 + wv * 32;
    int r0 = row0 + l15;      r0 = r0 < M ? r0 : M - 1;   // clamp; stores guarded
    int r1 = row0 + 16 + l15; r1 = r1 < M ? r1 : M - 1;

    bf8_t a1[2][4];                       // all A1 frags resident (32 VGPR)
    for (int kc = 0; kc < 4; kc++) {
        a1[0][kc] = *(const bf8_t*)(A + (size_t)r0 * 128 + kc * 32 + quad * 8);
        a1[1][kc] = *(const bf8_t*)(A + (size_t)r1 * 128 + kc * 32 + quad * 8);
    }
    f32x4 acc2[2][8];
    for (int i = 0; i < 2; i++)
        for (int j = 0; j < 8; j++) acc2[i][j] = (f32x4){0.f, 0.f, 0.f, 0.f};

    for (int c = 0; c < 8; c++) {         // 32-col chunk of h2 == 32-k of GEMM2
        f32x4 acc1[2][2];
        for (int i = 0; i < 2; i++)
            for (int j = 0; j < 2; j++) acc1[i][j] = (f32x4){0.f, 0.f, 0.f, 0.f};
        for (int kc = 0; kc < 4; kc++)
            for (int nt = 0; nt < 2; nt++) {
                bf8_t b = *(const bf8_t*)(Bt1 +
                    ((size_t)(kc * 4 + quad) * 256 + c * 32 + nt * 16 + l15) * 8);
                acc1[0][nt] = __builtin_amdgcn_mfma_f32_16x16x32_bf16(a1[0][kc], b, acc1[0][nt], 0, 0, 0);
                acc1[1][nt] = __builtin_amdgcn_mfma_f32_16x16x32_bf16(a1[1][kc], b, acc1[1][nt], 0, 0, 0);
            }
        for (int nt = 0; nt < 2; nt++) {
            float bb = b2[c * 32 + nt * 16 + l15];
            for (int mt = 0; mt < 2; mt++)
                for (int rg = 0; rg < 4; rg++)
                    st[wv][mt * 16 + quad * 4 + rg][nt * 16 + l15] =
                        f2bf(fmaxf(acc1[mt][nt][rg] + bb, 0.f));
        }
        bf8_t a2_0 = *(const bf8_t*)&st[wv][l15][quad * 8];
        bf8_t a2_1 = *(const bf8_t*)&st[wv][16 + l15][quad * 8];
        for (int nt2 = 0; nt2 < 8; nt2++) {
            bf8_t b = *(const bf8_t*)(Bt2 +
                ((size_t)(c * 4 + quad) * 128 + nt2 * 16 + l15) * 8);
            acc2[0][nt2] = __builtin_amdgcn_mfma_f32_16x16x32_bf16(a2_0, b, acc2[0][nt2], 0, 0, 0);
            acc2[1][nt2] = __builtin_amdgcn_mfma_f32_16x16x32_bf16(a2_1, b, acc2[1][nt2], 0, 0, 0);
        }
    }
    float rs[2][4] = {};
    for (int nt2 = 0; nt2 < 8; nt2++) {
        int col = nt2 * 16 + l15;
        float bb = bl1[col], ww = wl2[col];
        for (int mt = 0; mt < 2; mt++)
            for (int rg = 0; rg < 4; rg++)
                rs[mt][rg] += fmaxf(acc2[mt][nt2][rg] + bb, 0.f) * ww;
    }
    float base = bl2[0];
    for (int mt = 0; mt < 2; mt++)
        for (int rg = 0; rg < 4; rg++) {
            float s = rs[mt][rg];
            s += __shfl_xor(s, 1);
            s += __shfl_xor(s, 2);
            s += __shfl_xor(s, 4);
            s += __shfl_xor(s, 8);
            int row = row0 + mt * 16 + quad * 4 + rg;
            if (l15 == 0 && row < M) out[row] = s + base;
        }
}

extern "C" void kernel_launch(void* const* d_in, const int* in_sizes, int n_in,
                              void* d_out, int out_size, void* d_ws, size_t ws_size,
                              hipStream_t stream) {
    const float* x   = (const float*)d_in[0];
    const int*   ei  = (const int*)d_in[1];
    const float* ew  = (const float*)d_in[2];
    const float* W1  = (const float*)d_in[3];
    const float* b1  = (const float*)d_in[4];
    const float* W2  = (const float*)d_in[5];
    const float* b2  = (const float*)d_in[6];
    const float* Wl1 = (const float*)d_in[7];
    const float* bl1 = (const float*)d_in[8];
    const float* Wl2 = (const float*)d_in[9];
    const float* bl2 = (const float*)d_in[10];
    float* out = (float*)d_out;
    const int N = in_sizes[0];
    const int E = in_sizes[2];

    const int nbuck = (N + BNODES - 1) >> BSHIFT;             // 391
    const int cap = ((E / nbuck) * 5) / 4 + 1024;             // +~32 sigma slack

    char* w = (char*)d_ws;
    size_t off = 0;
    auto alloc = [&](size_t bytes) -> void* {
        void* p = w + off;
        off = align256(off + bytes);
        return p;
    };
    uint*   z      = (uint*)alloc((size_t)N * 64 * 4);      // bf16 [N][128]
    float2* tp     = (float2*)alloc((size_t)N * 8);         // (t, dis)
    float*  dis    = (float*)alloc((size_t)N * 4);
    float*  p_     = (float*)alloc((size_t)N * 4);
    int*    rowptr = (int*)alloc((size_t)(N + 1) * 4);
    int2*   cv     = (int2*)alloc((size_t)E * 8);
    uint2*  stg    = (uint2*)alloc((size_t)nbuck * cap * 8);
    int*    bfill  = (int*)alloc(512 * 4);
    int*    cvbase = (int*)alloc(512 * 4);
    ushort* Bt1    = (ushort*)alloc(32768 * 2);
    ushort* Bt2    = (ushort*)alloc(32768 * 2);

    hipMemsetAsync(bfill, 0, 512 * 4, stream);
    k_part<<<(E + 2047) / 2048, 256, 0, stream>>>(ei, ew, bfill, stg, E, nbuck, cap);
    k_bscan<<<1, 512, 0, stream>>>(bfill, cvbase, rowptr, nbuck, N, E);
    k_fine<<<nbuck, 512, 0, stream>>>(stg, bfill, cvbase, x, dis, p_, rowptr, cv, cap, N);
    k_prepB<<<128, 256, 0, stream>>>(W2, Wl1, Bt1, Bt2);
    k_q<<<(N * 16 + 255) / 256, 256, 0, stream>>>(rowptr, cv, dis, p_, tp, N);
    k_agg<<<(N + 3) / 4, 256, 0, stream>>>(rowptr, cv, tp, W1, b1, z, N);
    k_mlp<<<(N + 127) / 128, 256, 0, stream>>>((const ushort*)z, Bt1, Bt2,
                                               b2, bl1, Wl2, bl2, out, N);
}